// Round 7
// baseline (840.361 us; speedup 1.0000x reference)
//
#include <hip/hip_runtime.h>

#define NN    1024
#define STEPS 512
#define RPL   16   // rows per lane; 64 lanes * 16 = 1024 rows = one column per wave

// ---------- complex helpers ----------
__device__ __forceinline__ float2 cmul(float2 p, float2 q) {
    return make_float2(fmaf(p.x, q.x, -p.y * q.y), fmaf(p.x, q.y, p.y * q.x));
}
__device__ __forceinline__ float2 addi(float2 u, float2 v) {
    // u + i*v
    return make_float2(u.x - v.y, u.y + v.x);
}

// ---------- one full step on 16 register-resident rows ----------
// Step = even-MMI, heater(pa), even-MMI, odd-MMI, heater(pb), odd-MMI.
// ca[r] = 0.5 e^{i pa[r]} (heater pa + both even 1/sqrt2 scales).
// cb[r] = 0.5 e^{i pb[r]} interior; rows 0 / N-1 pass through both odd stages,
// so cb is e^{i pb[r]} unscaled there.
__device__ __forceinline__ void do_step(float2 (&m)[RPL],
                                        const float2 (&ca)[RPL],
                                        const float2 (&cb)[RPL],
                                        int t)
{
    // even1 (unscaled Bell): lane-internal pairs (j, j+1), j even
#pragma unroll
    for (int j = 0; j < RPL; j += 2) {
        float2 a = m[j], b = m[j + 1];
        m[j]     = addi(a, b);   // a + i b
        m[j + 1] = addi(b, a);   // i a + b
    }
    // heater(pa) + even2 (scales folded into ca)
#pragma unroll
    for (int j = 0; j < RPL; j += 2) {
        float2 u = cmul(ca[j],     m[j]);
        float2 v = cmul(ca[j + 1], m[j + 1]);
        m[j]     = addi(u, v);
        m[j + 1] = addi(v, u);
    }
    // odd1 (unscaled): pairs (j, j+1), j odd; boundary pair (m[15], next lane's m[0])
    float2 nb, pv;
    nb.x = __shfl_down(m[0].x, 1);        nb.y = __shfl_down(m[0].y, 1);
    pv.x = __shfl_up(m[RPL - 1].x, 1);    pv.y = __shfl_up(m[RPL - 1].y, 1);
#pragma unroll
    for (int j = 1; j < RPL - 1; j += 2) {
        float2 a = m[j], b = m[j + 1];
        m[j]     = addi(a, b);
        m[j + 1] = addi(b, a);
    }
    if (t < 63) m[RPL - 1] = addi(m[RPL - 1], nb);  // row 1023 passes through
    if (t > 0)  m[0]       = addi(m[0], pv);        // row 0    passes through
    // heater(pb) + odd2 (scales folded into cb)
    float2 u0  = cmul(cb[0],       m[0]);
    float2 u15 = cmul(cb[RPL - 1], m[RPL - 1]);
    float2 vn, up;
    vn.x = __shfl_down(u0.x, 1);   vn.y = __shfl_down(u0.y, 1);
    up.x = __shfl_up(u15.x, 1);    up.y = __shfl_up(u15.y, 1);
#pragma unroll
    for (int j = 1; j < RPL - 1; j += 2) {
        float2 u = cmul(cb[j],     m[j]);
        float2 v = cmul(cb[j + 1], m[j + 1]);
        m[j]     = addi(u, v);
        m[j + 1] = addi(v, u);
    }
    m[RPL - 1] = (t < 63) ? addi(u15, vn) : u15;
    m[0]       = (t > 0)  ? addi(u0, up)  : u0;
}

// ---------- main: one wave per column, column in registers, no workspace ----------
__global__ void __launch_bounds__(64, 1)
clements_real(const float* __restrict__ phases,
              float* __restrict__ outf,
              int out_size)
{
    const int c  = blockIdx.x;   // column
    const int t  = threadIdx.x;  // lane
    const int r0 = t * RPL;

    // M0 = heater(I, phases[0]): diagonal e^{i phases[0][c]} in row c
    float2 m[RPL];
    {
        float sv, cv; __sincosf(phases[c], &sv, &cv);
        const float2 diag = make_float2(cv, sv);
#pragma unroll
        for (int j = 0; j < RPL; ++j)
            m[j] = (r0 + j == c) ? diag : make_float2(0.f, 0.f);
    }

    for (int s = 0; s < STEPS; ++s) {
        // load rows (1+2s, 2+2s), 16 floats each, float4-coalesced (64B aligned)
        const float* pa = phases + (size_t)(1 + 2 * s) * NN + r0;
        const float* pb = pa + NN;
        float2 ca[RPL], cb[RPL];
#pragma unroll
        for (int q = 0; q < 4; ++q) {
            float4 va = reinterpret_cast<const float4*>(pa)[q];
            float4 vb = reinterpret_cast<const float4*>(pb)[q];
            float s0, c0;
            __sincosf(va.x, &s0, &c0); ca[4*q + 0] = make_float2(0.5f * c0, 0.5f * s0);
            __sincosf(va.y, &s0, &c0); ca[4*q + 1] = make_float2(0.5f * c0, 0.5f * s0);
            __sincosf(va.z, &s0, &c0); ca[4*q + 2] = make_float2(0.5f * c0, 0.5f * s0);
            __sincosf(va.w, &s0, &c0); ca[4*q + 3] = make_float2(0.5f * c0, 0.5f * s0);
            __sincosf(vb.x, &s0, &c0); cb[4*q + 0] = make_float2(0.5f * c0, 0.5f * s0);
            __sincosf(vb.y, &s0, &c0); cb[4*q + 1] = make_float2(0.5f * c0, 0.5f * s0);
            __sincosf(vb.z, &s0, &c0); cb[4*q + 2] = make_float2(0.5f * c0, 0.5f * s0);
            __sincosf(vb.w, &s0, &c0); cb[4*q + 3] = make_float2(0.5f * c0, 0.5f * s0);
        }
        // rows 0 and 1023 pass through both odd stages: cb unscaled there
        if (t == 0)  cb[0]       = make_float2(2.f * cb[0].x,       2.f * cb[0].y);
        if (t == 63) cb[RPL - 1] = make_float2(2.f * cb[RPL - 1].x, 2.f * cb[RPL - 1].y);

        do_step(m, ca, cb, t);
    }

    // final heater, then store REAL PART as float32, row-major [N][N],
    // bounds-guarded by runtime out_size (float elements)
    const float* pf = phases + (size_t)(NN + 1) * NN + r0;
#pragma unroll
    for (int j = 0; j < RPL; ++j) {
        float sf, cf; __sincosf(pf[j], &sf, &cf);
        float2 r = cmul(make_float2(cf, sf), m[j]);
        int idx = (r0 + j) * NN + c;
        if (idx < out_size) outf[idx] = r.x;
    }
}

extern "C" void kernel_launch(void* const* d_in, const int* in_sizes, int n_in,
                              void* d_out, int out_size, void* d_ws, size_t ws_size,
                              hipStream_t stream)
{
    (void)in_sizes; (void)n_in; (void)d_ws; (void)ws_size;
    const float* phases = (const float*)d_in[0];
    float* outf = (float*)d_out;

    hipLaunchKernelGGL(clements_real, dim3(NN), dim3(64), 0, stream,
                       phases, outf, out_size);
}